// Round 3
// baseline (1635.651 us; speedup 1.0000x reference)
//
#include <hip/hip_runtime.h>
#include <math.h>

#define D 128
#define N_RBF 6
#define A_DIM 49
#define N_BIL 8
#define N_EDGES 200000
#define N_ANGLES 1000000

#define BM 128           // edges per block in main kernel (tail block handles 200000 % 128 = 64)
#define THREADS 512      // 8 waves/block, 2 waves/SIMD at 1 block/CU
#define MROW 132         // padded LDS row stride for me tile (+4 floats -> 2-way max = free)

// XOR-swizzle for the [128][128] LDS operand buffer (T-slice / W_nbr^T).
// Read pattern: 16 lanes read rows i0=ti*8 (stride-8 rows) at the same column
// block -> unswizzled all rows start at bank 0 (128 floats/row % 32 == 0).
// XOR bits 2..4 of the column with bits 3..5 of the row -> the 16 rows map to
// 8 distinct float4 slots covering all 32 banks (2-way address alias = free).
__device__ __forceinline__ int swz(int row, int col) {
  return (row << 7) + (col ^ (((row >> 3) & 7) << 2));
}

// ---------------- Kernel 1: A[e,j] = sum_{w: kj[w]=e} (a_sbf[w,:] @ W_a)[j] --------------
__global__ __launch_bounds__(256) void k_accA(const float* __restrict__ a_sbf,
                                              const int* __restrict__ kj,
                                              const float* __restrict__ W_a,
                                              float* __restrict__ A) {
  __shared__ float wa[A_DIM * N_BIL];  // 392 floats, broadcast reads
  for (int i = threadIdx.x; i < A_DIM * N_BIL; i += 256) wa[i] = W_a[i];
  __syncthreads();
  int w = blockIdx.x * 256 + threadIdx.x;
  const int stride = gridDim.x * 256;
  for (; w < N_ANGLES; w += stride) {
    const float* ar = a_sbf + (size_t)w * A_DIM;
    float ta[N_BIL];
#pragma unroll
    for (int j = 0; j < N_BIL; ++j) ta[j] = 0.f;
#pragma unroll
    for (int k = 0; k < A_DIM; ++k) {
      const float av = ar[k];
#pragma unroll
      for (int j = 0; j < N_BIL; ++j) ta[j] = fmaf(av, wa[k * N_BIL + j], ta[j]);
    }
    const int e = kj[w];
    float* Ae = A + (size_t)e * N_BIL;
#pragma unroll
    for (int j = 0; j < N_BIL; ++j) atomicAdd(Ae + j, ta[j]);
  }
}

// ---------------- Kernel 2 (fused): me = silu(m@W_nbr + b) * (rbf@W_e);
//                  out[e,i] = sum_j A[e,j] * sum_l me[e,l] * T[i,j,l] ----------------------
__global__ __launch_bounds__(THREADS, 2) void k_main(const float* __restrict__ m_ji,
                                                     const float* __restrict__ e_rbf,
                                                     const float* __restrict__ W_nbr,
                                                     const float* __restrict__ b_nbr,
                                                     const float* __restrict__ W_e,
                                                     const float* __restrict__ T,
                                                     const float* __restrict__ A,
                                                     float* __restrict__ out) {
  __shared__ float me_lds[BM * MROW];     // 67584 B: m tile (phase A), then me tile (phase B)
  __shared__ float tjb[D * D];            // 65536 B: W_nbr^T (phase A) / T[:,j,:] (phase B), swizzled
  __shared__ float A_lds[BM * N_BIL];     // 4096 B
  __shared__ float we_lds[N_RBF * D];     // 3072 B
  __shared__ float erbf_lds[BM * N_RBF];  // 3072 B   -> total ~140 KB, 1 block/CU, 8 waves

  const int t = threadIdx.x;
  const int e0 = blockIdx.x * BM;
  const int tr = t >> 4;   // 0..31
  const int ti = t & 15;   // 0..15
  const int r0 = tr * 4;   // this thread's 4 edge rows (0..124)
  const int i0 = ti * 8;   // this thread's 8 output channels

  // ---- stage m tile (128 x 128), row-clamped for the tail block ----
  {
    const float4* gm = reinterpret_cast<const float4*>(m_ji);
#pragma unroll
    for (int it = 0; it < 8; ++it) {
      const int q = it * THREADS + t;
      const int r = q >> 5, c4 = q & 31;
      size_t grow = (size_t)(e0 + r);
      if (grow >= N_EDGES) grow = N_EDGES - 1;  // clamp: phantom rows never stored
      const float4 v = gm[grow * 32 + c4];
      *reinterpret_cast<float4*>(&me_lds[r * MROW + c4 * 4]) = v;
    }
  }
  // ---- stage W_nbr transposed+swizzled: tjb[i][k] = W_nbr[k][i] ----
  {
    const float4* gw = reinterpret_cast<const float4*>(W_nbr);
#pragma unroll
    for (int it = 0; it < 8; ++it) {
      const int q = it * THREADS + t;
      const int k = q >> 5, i4 = q & 31;
      const float4 v = gw[k * 32 + i4];
      tjb[swz(i4 * 4 + 0, k)] = v.x;
      tjb[swz(i4 * 4 + 1, k)] = v.y;
      tjb[swz(i4 * 4 + 2, k)] = v.z;
      tjb[swz(i4 * 4 + 3, k)] = v.w;
    }
  }
  // ---- small operands (clamped) ----
  for (int q = t; q < BM * N_RBF; q += THREADS) {
    size_t g = (size_t)e0 * N_RBF + q;
    if (g >= (size_t)N_EDGES * N_RBF) g = (size_t)N_EDGES * N_RBF - 1;
    erbf_lds[q] = e_rbf[g];
  }
  for (int q = t; q < N_RBF * D; q += THREADS) we_lds[q] = W_e[q];
  for (int q = t; q < BM * N_BIL; q += THREADS) {
    size_t g = (size_t)e0 * N_BIL + q;
    if (g >= (size_t)N_EDGES * N_BIL) g = (size_t)N_EDGES * N_BIL - 1;
    A_lds[q] = A[g];
  }
  __syncthreads();

  // ---- phase A: tm[4][8] = (m @ W_nbr) for this thread's (r,i) tile ----
  float tm[4][8];
#pragma unroll
  for (int a = 0; a < 4; ++a)
#pragma unroll
    for (int b = 0; b < 8; ++b) tm[a][b] = 0.f;

#pragma unroll 2
  for (int kc = 0; kc < 32; ++kc) {
    float4 mv[4];
#pragma unroll
    for (int rr = 0; rr < 4; ++rr)
      mv[rr] = *reinterpret_cast<const float4*>(&me_lds[(r0 + rr) * MROW + kc * 4]);
    float4 wv[8];
#pragma unroll
    for (int ii = 0; ii < 8; ++ii)
      wv[ii] = *reinterpret_cast<const float4*>(&tjb[swz(i0 + ii, kc * 4)]);
#pragma unroll
    for (int rr = 0; rr < 4; ++rr)
#pragma unroll
      for (int ii = 0; ii < 8; ++ii) {
        tm[rr][ii] = fmaf(mv[rr].x, wv[ii].x, tm[rr][ii]);
        tm[rr][ii] = fmaf(mv[rr].y, wv[ii].y, tm[rr][ii]);
        tm[rr][ii] = fmaf(mv[rr].z, wv[ii].z, tm[rr][ii]);
        tm[rr][ii] = fmaf(mv[rr].w, wv[ii].w, tm[rr][ii]);
      }
  }

  // ---- silu(tm + b) * (rbf @ W_e) -> me ----
  float bi[8];
#pragma unroll
  for (int ii = 0; ii < 8; ++ii) bi[ii] = b_nbr[i0 + ii];
  float me[4][8];
#pragma unroll
  for (int rr = 0; rr < 4; ++rr)
#pragma unroll
    for (int ii = 0; ii < 8; ++ii) {
      const float x = tm[rr][ii] + bi[ii];
      const float s = x / (1.f + expf(-x));   // precise exp: match jax.nn.silu closely
      float te = 0.f;
#pragma unroll
      for (int q = 0; q < N_RBF; ++q)
        te = fmaf(erbf_lds[(r0 + rr) * N_RBF + q], we_lds[q * D + i0 + ii], te);
      me[rr][ii] = s * te;
    }
  __syncthreads();  // all phase-A reads of the m tile done before overwrite
#pragma unroll
  for (int rr = 0; rr < 4; ++rr)
#pragma unroll
    for (int ii = 0; ii < 8; ++ii) me_lds[(r0 + rr) * MROW + i0 + ii] = me[rr][ii];

  // ---- phase B: acc[r][i] = sum_j A[r][j] * (sum_l me[r][l] * T[i,j,l]) ----
  float acc[4][8];
#pragma unroll
  for (int a = 0; a < 4; ++a)
#pragma unroll
    for (int b = 0; b < 8; ++b) acc[a][b] = 0.f;

  for (int j = 0; j < N_BIL; ++j) {
    __syncthreads();  // previous tjb readers done (j=0: covers me-tile writes too)
    // stage T[:, j, :] (128 x 128) swizzled; T layout [i][j][l]
#pragma unroll
    for (int it = 0; it < 8; ++it) {
      const int q = it * THREADS + t;
      const int i = q >> 5, l4 = q & 31;
      const float4 v =
          *reinterpret_cast<const float4*>(&T[((size_t)i * N_BIL + j) * D + l4 * 4]);
      *reinterpret_cast<float4*>(&tjb[swz(i, l4 * 4)]) = v;
    }
    __syncthreads();

    float P[4][8];
#pragma unroll
    for (int a = 0; a < 4; ++a)
#pragma unroll
      for (int b = 0; b < 8; ++b) P[a][b] = 0.f;

#pragma unroll 2
    for (int lc = 0; lc < 32; ++lc) {
      float4 mev[4];
#pragma unroll
      for (int rr = 0; rr < 4; ++rr)
        mev[rr] = *reinterpret_cast<const float4*>(&me_lds[(r0 + rr) * MROW + lc * 4]);
      float4 tv[8];
#pragma unroll
      for (int ii = 0; ii < 8; ++ii)
        tv[ii] = *reinterpret_cast<const float4*>(&tjb[swz(i0 + ii, lc * 4)]);
#pragma unroll
      for (int rr = 0; rr < 4; ++rr)
#pragma unroll
        for (int ii = 0; ii < 8; ++ii) {
          P[rr][ii] = fmaf(mev[rr].x, tv[ii].x, P[rr][ii]);
          P[rr][ii] = fmaf(mev[rr].y, tv[ii].y, P[rr][ii]);
          P[rr][ii] = fmaf(mev[rr].z, tv[ii].z, P[rr][ii]);
          P[rr][ii] = fmaf(mev[rr].w, tv[ii].w, P[rr][ii]);
        }
    }
#pragma unroll
    for (int rr = 0; rr < 4; ++rr) {
      const float aj = A_lds[(r0 + rr) * N_BIL + j];
#pragma unroll
      for (int ii = 0; ii < 8; ++ii) acc[rr][ii] = fmaf(aj, P[rr][ii], acc[rr][ii]);
    }
  }

  // ---- store (guarded for the tail block) ----
#pragma unroll
  for (int rr = 0; rr < 4; ++rr) {
    const int erow = e0 + r0 + rr;
    if (erow < N_EDGES) {
      float4 o0 = make_float4(acc[rr][0], acc[rr][1], acc[rr][2], acc[rr][3]);
      float4 o1 = make_float4(acc[rr][4], acc[rr][5], acc[rr][6], acc[rr][7]);
      float* op = out + (size_t)erow * D + i0;
      *reinterpret_cast<float4*>(op) = o0;
      *reinterpret_cast<float4*>(op + 4) = o1;
    }
  }
}

extern "C" void kernel_launch(void* const* d_in, const int* in_sizes, int n_in,
                              void* d_out, int out_size, void* d_ws, size_t ws_size,
                              hipStream_t stream) {
  const float* m_ji  = (const float*)d_in[0];
  // d_in[1] nbr_list, d_in[2] angle_list: unused by the math
  const float* e_rbf = (const float*)d_in[3];
  const float* a_sbf = (const float*)d_in[4];
  const int*   kj    = (const int*)d_in[5];
  const float* W_nbr = (const float*)d_in[6];
  const float* b_nbr = (const float*)d_in[7];
  const float* W_e   = (const float*)d_in[8];
  const float* W_a   = (const float*)d_in[9];
  const float* T     = (const float*)d_in[10];

  float* A   = (float*)d_ws;           // [N_EDGES][N_BIL] = 6.4 MB scratch
  float* out = (float*)d_out;

  hipMemsetAsync(A, 0, (size_t)N_EDGES * N_BIL * sizeof(float), stream);
  k_accA<<<(N_ANGLES + 255) / 256, 256, 0, stream>>>(a_sbf, kj, W_a, A);
  k_main<<<(N_EDGES + BM - 1) / BM, THREADS, 0, stream>>>(m_ji, e_rbf, W_nbr, b_nbr, W_e,
                                                          T, A, out);
}